// Round 2
// baseline (1540.133 us; speedup 1.0000x reference)
//
#include <hip/hip_runtime.h>

#define B_ 2
#define S_ 2048
#define HID_ 4096
#define NH_ 32
#define NKV_ 8
#define D_ 128
#define M_ (B_*S_)                  // 4096 rows of hidden
#define NQKV_ (HID_ + 2*NKV_*D_)    // 6144

typedef __bf16 v8bf __attribute__((ext_vector_type(8)));
typedef float  v4f  __attribute__((ext_vector_type(4)));
typedef unsigned short v8us __attribute__((ext_vector_type(8)));

__device__ __forceinline__ unsigned short f2bf(float x) {
    unsigned u = __float_as_uint(x);
    u += 0x7FFFu + ((u >> 16) & 1u);   // RNE
    return (unsigned short)(u >> 16);
}
__device__ __forceinline__ float bf2f(unsigned short h) {
    return __uint_as_float(((unsigned)h) << 16);
}

// ---------------- fp32 -> bf16 elementwise convert (x4 vectorized) ---------
__global__ __launch_bounds__(256)
void cvt_f32_bf16(const float* __restrict__ src, unsigned short* __restrict__ dst, int n4) {
    int i = blockIdx.x * 256 + threadIdx.x;
    if (i >= n4) return;
    float4 v = ((const float4*)src)[i];
    ushort4 o;
    o.x = f2bf(v.x); o.y = f2bf(v.y); o.z = f2bf(v.z); o.w = f2bf(v.w);
    ((ushort4*)dst)[i] = o;
}

// ------------- transpose+convert: dst[n][k] = bf16(src[k][n]), fp32 src ----
__global__ __launch_bounds__(256)
void transpose_f32_bf16(const float* __restrict__ src,
                        unsigned short* __restrict__ dst, int K, int N) {
    __shared__ unsigned short tile[64][65];
    int n0 = blockIdx.x * 64, k0 = blockIdx.y * 64;
    int tid = threadIdx.x;
    for (int i = 0; i < 16; ++i) {
        int fi = tid + i * 256;
        int r = fi >> 6, c = fi & 63;
        tile[r][c] = f2bf(src[(size_t)(k0 + r) * N + n0 + c]);
    }
    __syncthreads();
    for (int i = 0; i < 16; ++i) {
        int fi = tid + i * 256;
        int r = fi >> 6, c = fi & 63;
        dst[(size_t)(n0 + r) * K + k0 + c] = tile[c][r];
    }
}

// ---------------- GEMM: C[M][N] = A[M][K] * BT[N][K]^T  (bf16 in, fp32 acc) -
// MODE 0: scatter epilogue into Q/K/V per-head bf16 buffers (pre-RoPE)
// MODE 1: fp32 store to outF, row stride HID_
template <int MODE>
__global__ __launch_bounds__(256)
void gemm_bt(const unsigned short* __restrict__ A,
             const unsigned short* __restrict__ BT,
             int K, int lda, int ldb,
             unsigned short* __restrict__ outQ,
             unsigned short* __restrict__ outK,
             unsigned short* __restrict__ outV,
             float* __restrict__ outF) {
    __shared__ unsigned short As[128][40];   // 80B row stride, 16B aligned
    __shared__ unsigned short Bs[128][40];
    int tid = threadIdx.x;
    int lane = tid & 63, wid = tid >> 6;
    int quad = lane >> 4, l16 = lane & 15;
    int wr = wid >> 1, wc = wid & 1;
    int r0 = blockIdx.y * 128, n0 = blockIdx.x * 128;

    v4f zero = {0.f, 0.f, 0.f, 0.f};
    v4f acc[4][4];
    for (int i = 0; i < 4; ++i) for (int j = 0; j < 4; ++j) acc[i][j] = zero;

    const int cr = tid >> 2, cc = tid & 3;   // staging: row, 16B-chunk col
    for (int kt = 0; kt < K / 32; ++kt) {
        int kk = kt * 32;
        *(uint4*)&As[cr     ][cc * 8] = *(const uint4*)&A [(size_t)(r0 + cr     ) * lda + kk + cc * 8];
        *(uint4*)&As[cr + 64][cc * 8] = *(const uint4*)&A [(size_t)(r0 + cr + 64) * lda + kk + cc * 8];
        *(uint4*)&Bs[cr     ][cc * 8] = *(const uint4*)&BT[(size_t)(n0 + cr     ) * ldb + kk + cc * 8];
        *(uint4*)&Bs[cr + 64][cc * 8] = *(const uint4*)&BT[(size_t)(n0 + cr + 64) * ldb + kk + cc * 8];
        __syncthreads();
        v8bf av[4], bv[4];
        for (int ms = 0; ms < 4; ++ms) av[ms] = *(const v8bf*)&As[wr * 64 + ms * 16 + l16][quad * 8];
        for (int ns = 0; ns < 4; ++ns) bv[ns] = *(const v8bf*)&Bs[wc * 64 + ns * 16 + l16][quad * 8];
        for (int ms = 0; ms < 4; ++ms)
            for (int ns = 0; ns < 4; ++ns)
                acc[ms][ns] = __builtin_amdgcn_mfma_f32_16x16x32_bf16(av[ms], bv[ns], acc[ms][ns], 0, 0, 0);
        __syncthreads();
    }

    for (int ms = 0; ms < 4; ++ms)
        for (int ns = 0; ns < 4; ++ns)
            for (int r = 0; r < 4; ++r) {
                int row = r0 + wr * 64 + ms * 16 + quad * 4 + r;   // C row = quad*4+reg (m89)
                int col = n0 + wc * 64 + ns * 16 + l16;            // C col = lane&15
                if (MODE == 1) {
                    outF[(size_t)row * HID_ + col] = acc[ms][ns][r];
                } else {
                    unsigned short hv = f2bf(acc[ms][ns][r]);
                    int b = row >> 11, s = row & (S_ - 1);
                    if (col < HID_) {
                        int h = col >> 7, d = col & 127;
                        outQ[((size_t)((b * NH_ + h) * S_ + s)) * D_ + d] = hv;
                    } else if (col < HID_ + NKV_ * D_) {
                        int j = col - HID_; int h = j >> 7, d = j & 127;
                        outK[((size_t)((b * NKV_ + h) * S_ + s)) * D_ + d] = hv;
                    } else {
                        int j = col - HID_ - NKV_ * D_; int h = j >> 7, d = j & 127;
                        outV[((size_t)((b * NKV_ + h) * S_ + s)) * D_ + d] = hv;
                    }
                }
            }
}

// ---------------- RoPE in-place on [BH][S][D] bf16, fp32 cos/sin ----------
__global__ __launch_bounds__(256)
void rope_kernel(unsigned short* __restrict__ buf,
                 const float* __restrict__ cosc,
                 const float* __restrict__ sinc, int total) {
    int idx = blockIdx.x * 256 + threadIdx.x;
    if (idx >= total) return;
    int d2 = idx & 63;
    int s  = (idx >> 6) & (S_ - 1);
    int bh = idx >> 17;                       // /(64*2048)
    size_t base = ((size_t)bh * S_ + s) * D_;
    float c  = cosc[s * D_ + d2];             // cos[s][d2] == cos[s][d2+64]
    float sn = sinc[s * D_ + d2];
    float x1 = bf2f(buf[base + d2]);
    float x2 = bf2f(buf[base + d2 + 64]);
    buf[base + d2]      = f2bf(x1 * c - x2 * sn);
    buf[base + d2 + 64] = f2bf(x2 * c + x1 * sn);
}

// ---------------- causal flash attention ----------------------------------
// grid: (S/64, NH, B). block: 256 (4 waves x 16 q-rows). KV tile = 32.
__global__ __launch_bounds__(256)
void flash_attn(const unsigned short* __restrict__ Q,
                const unsigned short* __restrict__ Kb,
                const unsigned short* __restrict__ Vb,
                unsigned short* __restrict__ O) {
    __shared__ unsigned short Ks[32][136];    // [key][d]
    __shared__ unsigned short Vt[128][40];    // [d][key]
    __shared__ unsigned short Ps[4][16][40];  // per-wave P relayout scratch
    int tid = threadIdx.x;
    int lane = tid & 63, w = tid >> 6;
    int quad = lane >> 4, l16 = lane & 15;
    int qt = blockIdx.x, h = blockIdx.y, b = blockIdx.z;
    int qbase = qt * 64 + w * 16;

    const size_t qoff = ((size_t)(b * NH_ + h) * S_ + qbase + l16) * D_;
    v8bf aq[4];
    for (int kt = 0; kt < 4; ++kt) aq[kt] = *(const v8bf*)&Q[qoff + kt * 32 + quad * 8];

    const size_t kvbase = (size_t)(b * NKV_ + (h >> 2)) * S_ * D_;  // GROUPS=4

    v4f zero = {0.f, 0.f, 0.f, 0.f};
    v4f o[8];
    for (int i = 0; i < 8; ++i) o[i] = zero;
    float m_[4] = {-1e30f, -1e30f, -1e30f, -1e30f};
    float l_[4] = {0.f, 0.f, 0.f, 0.f};

    int ntiles = qt * 2 + 2;                  // causal: only tiles with kv0 <= qmax
    for (int t = 0; t < ntiles; ++t) {
        int kv0 = t * 32;
        __syncthreads();                      // protect Ks/Vt from previous iter readers
        for (int i = 0; i < 2; ++i) {
            int cch = tid + i * 256;          // 512 chunks of 8 bf16
            int row = cch >> 4, cq = cch & 15;
            const size_t src = kvbase + (size_t)(kv0 + row) * D_ + cq * 8;
            *(uint4*)&Ks[row][cq * 8] = *(const uint4*)&Kb[src];
            v8us vv = *(const v8us*)&Vb[src];
            for (int j = 0; j < 8; ++j) Vt[cq * 8 + j][row] = vv[j];
        }
        __syncthreads();

        // S = Q K^T for 16 q-rows x 32 keys
        v4f sa[2]; sa[0] = zero; sa[1] = zero;
        for (int ks = 0; ks < 2; ++ks)
            for (int kt = 0; kt < 4; ++kt) {
                v8bf bk = *(const v8bf*)&Ks[ks * 16 + l16][kt * 32 + quad * 8];
                sa[ks] = __builtin_amdgcn_mfma_f32_16x16x32_bf16(aq[kt], bk, sa[ks], 0, 0, 0);
            }

        const float scale = 0.08838834764831845f;  // 1/sqrt(128)
        float pv0[4], pv1[4], al[4];
        for (int r = 0; r < 4; ++r) {
            int qrow = qbase + quad * 4 + r;
            float s0 = sa[0][r] * scale, s1 = sa[1][r] * scale;
            if (kv0 + l16 > qrow)      s0 = -1e30f;
            if (kv0 + 16 + l16 > qrow) s1 = -1e30f;
            float rm = fmaxf(s0, s1);
            rm = fmaxf(rm, __shfl_xor(rm, 1));
            rm = fmaxf(rm, __shfl_xor(rm, 2));
            rm = fmaxf(rm, __shfl_xor(rm, 4));
            rm = fmaxf(rm, __shfl_xor(rm, 8));
            float mn = fmaxf(m_[r], rm);
            al[r] = __expf(m_[r] - mn);
            float p0 = __expf(s0 - mn), p1 = __expf(s1 - mn);
            pv0[r] = p0; pv1[r] = p1;
            float rs = p0 + p1;
            rs += __shfl_xor(rs, 1);
            rs += __shfl_xor(rs, 2);
            rs += __shfl_xor(rs, 4);
            rs += __shfl_xor(rs, 8);
            l_[r] = l_[r] * al[r] + rs;
            m_[r] = mn;
        }
        for (int i = 0; i < 8; ++i)
            for (int r = 0; r < 4; ++r) o[i][r] *= al[r];

        // P: C-layout -> A-layout via LDS (per-wave scratch, same-wave ordered)
        for (int r = 0; r < 4; ++r) {
            Ps[w][quad * 4 + r][l16]      = f2bf(pv0[r]);
            Ps[w][quad * 4 + r][16 + l16] = f2bf(pv1[r]);
        }
        v8bf pa = *(const v8bf*)&Ps[w][l16][quad * 8];
        for (int n8 = 0; n8 < 8; ++n8) {
            v8bf bv = *(const v8bf*)&Vt[n8 * 16 + l16][quad * 8];
            o[n8] = __builtin_amdgcn_mfma_f32_16x16x32_bf16(pa, bv, o[n8], 0, 0, 0);
        }
    }

    for (int n8 = 0; n8 < 8; ++n8)
        for (int r = 0; r < 4; ++r) {
            int qg = qbase + quad * 4 + r;
            float val = o[n8][r] / l_[r];
            O[((size_t)(b * S_ + qg)) * HID_ + h * D_ + n8 * 16 + l16] = f2bf(val);
        }
}

// ---------------- launcher ------------------------------------------------
extern "C" void kernel_launch(void* const* d_in, const int* in_sizes, int n_in,
                              void* d_out, int out_size, void* d_ws, size_t ws_size,
                              hipStream_t stream) {
    const float* hid  = (const float*)d_in[0];
    const float* Wq   = (const float*)d_in[1];
    const float* Wk   = (const float*)d_in[2];
    const float* Wv   = (const float*)d_in[3];
    const float* Wo   = (const float*)d_in[4];
    const float* cosc = (const float*)d_in[5];
    const float* sinc = (const float*)d_in[6];
    // d_in[7] position_ids == arange, d_in[8] attention_mask == causal: implicit

    unsigned short* ws    = (unsigned short*)d_ws;
    // element offsets (bf16 = 2B each)
    unsigned short* wqkvT = ws;                                    // [6144][4096]  50.33 MB
    unsigned short* qbuf  = ws + (size_t)NQKV_ * HID_;             // [2][32][2048][128] 33.55 MB
    unsigned short* kbuf  = qbuf + (size_t)B_ * NH_ * S_ * D_;     // 8.39 MB
    unsigned short* vbuf  = kbuf + (size_t)B_ * NKV_ * S_ * D_;    // 8.39 MB
    unsigned short* hidB  = vbuf + (size_t)B_ * NKV_ * S_ * D_;    // [4096][4096] 33.55 MB -> peak 134.3 MB
    unsigned short* attn  = ws;                                    // alias wqkvT[0:16.78M] (dead after gemm1)
    unsigned short* woT   = ws + (size_t)M_ * HID_;                // alias wqkvT tail + qbuf head (dead after flash)

    // 1. hidden fp32 -> bf16
    cvt_f32_bf16<<<(M_ * HID_ / 4 + 255) / 256, 256, 0, stream>>>(hid, hidB, M_ * HID_ / 4);
    // 2. W^T staging: Wq|Wk|Wv transposed + converted
    transpose_f32_bf16<<<dim3(64, 64), 256, 0, stream>>>(Wq, wqkvT, HID_, HID_);
    transpose_f32_bf16<<<dim3(16, 64), 256, 0, stream>>>(Wk, wqkvT + (size_t)HID_ * HID_, HID_, NKV_ * D_);
    transpose_f32_bf16<<<dim3(16, 64), 256, 0, stream>>>(Wv, wqkvT + (size_t)(HID_ + NKV_ * D_) * HID_, HID_, NKV_ * D_);
    // 3. fused QKV projection, scatter to per-head layouts
    gemm_bt<0><<<dim3(NQKV_ / 128, M_ / 128), 256, 0, stream>>>(
        hidB, wqkvT, HID_, HID_, HID_, qbuf, kbuf, vbuf, nullptr);
    // 4. RoPE (in-place)
    rope_kernel<<<(B_ * NH_ * S_ * 64) / 256, 256, 0, stream>>>(qbuf, cosc, sinc, B_ * NH_ * S_ * 64);
    rope_kernel<<<(B_ * NKV_ * S_ * 64) / 256, 256, 0, stream>>>(kbuf, cosc, sinc, B_ * NKV_ * S_ * 64);
    // 5. causal flash attention -> attn [b,s,h*d] bf16 (reuses wqkvT region)
    flash_attn<<<dim3(S_ / 64, NH_, B_), 256, 0, stream>>>(qbuf, kbuf, vbuf, attn);
    // 6. O projection: transpose Wo (after flash: qbuf region dead), then GEMM -> fp32 out
    transpose_f32_bf16<<<dim3(64, 64), 256, 0, stream>>>(Wo, woT, HID_, HID_);
    gemm_bt<1><<<dim3(HID_ / 128, M_ / 128), 256, 0, stream>>>(
        attn, woT, HID_, HID_, HID_, nullptr, nullptr, nullptr, (float*)d_out);
}

// Round 3
// 1372.101 us; speedup vs baseline: 1.1225x; 1.1225x over previous
//
#include <hip/hip_runtime.h>

#define B_ 2
#define S_ 2048
#define HID_ 4096
#define NH_ 32
#define NKV_ 8
#define D_ 128
#define M_ (B_*S_)                  // 4096 rows of hidden
#define NQKV_ (HID_ + 2*NKV_*D_)    // 6144

typedef __bf16 v8bf __attribute__((ext_vector_type(8)));
typedef float  v4f  __attribute__((ext_vector_type(4)));

__device__ __forceinline__ unsigned short f2bf(float x) {
    unsigned u = __float_as_uint(x);
    u += 0x7FFFu + ((u >> 16) & 1u);   // RNE
    return (unsigned short)(u >> 16);
}
__device__ __forceinline__ float bf2f(unsigned short h) {
    return __uint_as_float(((unsigned)h) << 16);
}

// ---------------- fp32 -> bf16 elementwise convert (x4 vectorized) ---------
__global__ __launch_bounds__(256)
void cvt_f32_bf16(const float* __restrict__ src, unsigned short* __restrict__ dst, int n4) {
    int i = blockIdx.x * 256 + threadIdx.x;
    if (i >= n4) return;
    float4 v = ((const float4*)src)[i];
    ushort4 o;
    o.x = f2bf(v.x); o.y = f2bf(v.y); o.z = f2bf(v.z); o.w = f2bf(v.w);
    ((ushort4*)dst)[i] = o;
}

// ------------- transpose+convert: dst[n][k] = bf16(src[k][n]), fp32 src ----
__global__ __launch_bounds__(256)
void transpose_f32_bf16(const float* __restrict__ src,
                        unsigned short* __restrict__ dst, int K, int N) {
    __shared__ unsigned short tile[64][65];
    int n0 = blockIdx.x * 64, k0 = blockIdx.y * 64;
    int tid = threadIdx.x;
    for (int i = 0; i < 16; ++i) {
        int fi = tid + i * 256;
        int r = fi >> 6, c = fi & 63;
        tile[r][c] = f2bf(src[(size_t)(k0 + r) * N + n0 + c]);
    }
    __syncthreads();
    for (int i = 0; i < 16; ++i) {
        int fi = tid + i * 256;
        int r = fi >> 6, c = fi & 63;
        dst[(size_t)(n0 + r) * K + k0 + c] = tile[c][r];
    }
}

// ------------- per-head V transpose: [BHkv][S][D] -> [BHkv][D][S] bf16 -----
__global__ __launch_bounds__(256)
void transpose_v(const unsigned short* __restrict__ src,
                 unsigned short* __restrict__ dst) {
    __shared__ unsigned short tile[64][65];
    int s0 = blockIdx.x * 64, d0 = blockIdx.y * 64;
    size_t base = (size_t)blockIdx.z * S_ * D_;
    int tid = threadIdx.x;
    for (int i = 0; i < 16; ++i) {
        int fi = tid + i * 256;
        int r = fi >> 6, c = fi & 63;            // r: s-offset, c: d-offset
        tile[r][c] = src[base + (size_t)(s0 + r) * D_ + d0 + c];
    }
    __syncthreads();
    for (int i = 0; i < 16; ++i) {
        int fi = tid + i * 256;
        int r = fi >> 6, c = fi & 63;            // r: d-offset, c: s-offset
        dst[base + (size_t)(d0 + r) * S_ + s0 + c] = tile[c][r];
    }
}

// ---------------- GEMM: C[M][N] = A[M][K] * BT[N][K]^T  (bf16 in, fp32 acc) -
// MODE 0: scatter epilogue into Q/K/V per-head bf16 buffers (pre-RoPE)
// MODE 1: fp32 store to outF, row stride HID_
template <int MODE>
__global__ __launch_bounds__(256)
void gemm_bt(const unsigned short* __restrict__ A,
             const unsigned short* __restrict__ BT,
             int K, int lda, int ldb,
             unsigned short* __restrict__ outQ,
             unsigned short* __restrict__ outK,
             unsigned short* __restrict__ outV,
             float* __restrict__ outF) {
    __shared__ unsigned short As[128][40];   // 80B row stride, 16B aligned
    __shared__ unsigned short Bs[128][40];
    int tid = threadIdx.x;
    int lane = tid & 63, wid = tid >> 6;
    int quad = lane >> 4, l16 = lane & 15;
    int wr = wid >> 1, wc = wid & 1;
    int r0 = blockIdx.y * 128, n0 = blockIdx.x * 128;

    v4f zero = {0.f, 0.f, 0.f, 0.f};
    v4f acc[4][4];
    for (int i = 0; i < 4; ++i) for (int j = 0; j < 4; ++j) acc[i][j] = zero;

    const int cr = tid >> 2, cc = tid & 3;   // staging: row, 16B-chunk col
    for (int kt = 0; kt < K / 32; ++kt) {
        int kk = kt * 32;
        *(uint4*)&As[cr     ][cc * 8] = *(const uint4*)&A [(size_t)(r0 + cr     ) * lda + kk + cc * 8];
        *(uint4*)&As[cr + 64][cc * 8] = *(const uint4*)&A [(size_t)(r0 + cr + 64) * lda + kk + cc * 8];
        *(uint4*)&Bs[cr     ][cc * 8] = *(const uint4*)&BT[(size_t)(n0 + cr     ) * ldb + kk + cc * 8];
        *(uint4*)&Bs[cr + 64][cc * 8] = *(const uint4*)&BT[(size_t)(n0 + cr + 64) * ldb + kk + cc * 8];
        __syncthreads();
        v8bf av[4], bv[4];
        for (int ms = 0; ms < 4; ++ms) av[ms] = *(const v8bf*)&As[wr * 64 + ms * 16 + l16][quad * 8];
        for (int ns = 0; ns < 4; ++ns) bv[ns] = *(const v8bf*)&Bs[wc * 64 + ns * 16 + l16][quad * 8];
        for (int ms = 0; ms < 4; ++ms)
            for (int ns = 0; ns < 4; ++ns)
                acc[ms][ns] = __builtin_amdgcn_mfma_f32_16x16x32_bf16(av[ms], bv[ns], acc[ms][ns], 0, 0, 0);
        __syncthreads();
    }

    for (int ms = 0; ms < 4; ++ms)
        for (int ns = 0; ns < 4; ++ns)
            for (int r = 0; r < 4; ++r) {
                int row = r0 + wr * 64 + ms * 16 + quad * 4 + r;   // C row = quad*4+reg (m89)
                int col = n0 + wc * 64 + ns * 16 + l16;            // C col = lane&15
                if (MODE == 1) {
                    outF[(size_t)row * HID_ + col] = acc[ms][ns][r];
                } else {
                    unsigned short hv = f2bf(acc[ms][ns][r]);
                    int b = row >> 11, s = row & (S_ - 1);
                    if (col < HID_) {
                        int h = col >> 7, d = col & 127;
                        outQ[((size_t)((b * NH_ + h) * S_ + s)) * D_ + d] = hv;
                    } else if (col < HID_ + NKV_ * D_) {
                        int j = col - HID_; int h = j >> 7, d = j & 127;
                        outK[((size_t)((b * NKV_ + h) * S_ + s)) * D_ + d] = hv;
                    } else {
                        int j = col - HID_ - NKV_ * D_; int h = j >> 7, d = j & 127;
                        outV[((size_t)((b * NKV_ + h) * S_ + s)) * D_ + d] = hv;
                    }
                }
            }
}

// ---------------- RoPE in-place on [BH][S][D] bf16, fp32 cos/sin ----------
__global__ __launch_bounds__(256)
void rope_kernel(unsigned short* __restrict__ buf,
                 const float* __restrict__ cosc,
                 const float* __restrict__ sinc, int total) {
    int idx = blockIdx.x * 256 + threadIdx.x;
    if (idx >= total) return;
    int d2 = idx & 63;
    int s  = (idx >> 6) & (S_ - 1);
    int bh = idx >> 17;                       // /(64*2048)
    size_t base = ((size_t)bh * S_ + s) * D_;
    float c  = cosc[s * D_ + d2];             // cos[s][d2] == cos[s][d2+64]
    float sn = sinc[s * D_ + d2];
    float x1 = bf2f(buf[base + d2]);
    float x2 = bf2f(buf[base + d2 + 64]);
    buf[base + d2]      = f2bf(x1 * c - x2 * sn);
    buf[base + d2 + 64] = f2bf(x2 * c + x1 * sn);
}

// ---------------- causal flash attention v2 --------------------------------
// grid: (S/64, NH, B). block: 256 (4 waves x 16 q-rows). KV tile = 64 keys.
// K in [BHkv][S][D]; V pre-transposed to [BHkv][D][S]. Register prefetch.
__global__ __launch_bounds__(256)
void flash_attn(const unsigned short* __restrict__ Q,
                const unsigned short* __restrict__ Kb,
                const unsigned short* __restrict__ VT,
                unsigned short* __restrict__ O) {
    __shared__ unsigned short Ks[64][136];    // [key][d], stride 68 words ≡ 4 mod 32
    __shared__ unsigned short Vt[128][72];    // [d][key], stride 36 words ≡ 4 mod 32
    __shared__ unsigned short Ps[4][16][72];  // per-wave P scratch, stride 36 words
    int tid = threadIdx.x;
    int lane = tid & 63, w = tid >> 6;
    int quad = lane >> 4, l16 = lane & 15;
    int qt = blockIdx.x, h = blockIdx.y, b = blockIdx.z;
    int qbase = qt * 64 + w * 16;

    const size_t qoff = ((size_t)(b * NH_ + h) * S_ + qbase + l16) * D_;
    v8bf aq[4];
    for (int kt = 0; kt < 4; ++kt) aq[kt] = *(const v8bf*)&Q[qoff + kt * 32 + quad * 8];

    const int hkv = h >> 2;                                  // GROUPS=4
    const size_t kvbase = (size_t)(b * NKV_ + hkv) * S_ * D_;
    const size_t vtbase = kvbase;                            // same extent, [D][S]

    // staging assignments (4 uint4 each for K and V^T per thread)
    int krow[4], kch[4], vrow[4], vch[4];
    for (int i = 0; i < 4; ++i) {
        int idx = tid + i * 256;
        krow[i] = idx >> 4; kch[i] = idx & 15;   // 64 rows x 16 chunks
        vrow[i] = idx >> 3; vch[i] = idx & 7;    // 128 rows x 8 chunks
    }

    v4f zero = {0.f, 0.f, 0.f, 0.f};
    v4f o[8];
    for (int i = 0; i < 8; ++i) o[i] = zero;
    float m_[4] = {-1e30f, -1e30f, -1e30f, -1e30f};
    float l_[4] = {0.f, 0.f, 0.f, 0.f};

    const int ntiles = qt + 1;
    // prefetch tile 0
    uint4 kpre[4], vpre[4];
    for (int i = 0; i < 4; ++i) {
        kpre[i] = *(const uint4*)&Kb[kvbase + (size_t)krow[i] * D_ + kch[i] * 8];
        vpre[i] = *(const uint4*)&VT[vtbase + (size_t)vrow[i] * S_ + vch[i] * 8];
    }

    for (int t = 0; t < ntiles; ++t) {
        int kv0 = t * 64;
        __syncthreads();                      // previous tile's readers done
        for (int i = 0; i < 4; ++i) {
            *(uint4*)&Ks[krow[i]][kch[i] * 8] = kpre[i];
            *(uint4*)&Vt[vrow[i]][vch[i] * 8] = vpre[i];
        }
        __syncthreads();
        if (t + 1 < ntiles) {                 // prefetch next tile (overlaps compute)
            int nkv0 = kv0 + 64;
            for (int i = 0; i < 4; ++i) {
                kpre[i] = *(const uint4*)&Kb[kvbase + (size_t)(nkv0 + krow[i]) * D_ + kch[i] * 8];
                vpre[i] = *(const uint4*)&VT[vtbase + (size_t)vrow[i] * S_ + nkv0 + vch[i] * 8];
            }
        }

        // S = Q K^T : 16 q-rows x 64 keys (4 key-16-groups)
        v4f sa[4];
        for (int kg = 0; kg < 4; ++kg) sa[kg] = zero;
        for (int kg = 0; kg < 4; ++kg)
            for (int kt = 0; kt < 4; ++kt) {
                v8bf bk = *(const v8bf*)&Ks[kg * 16 + l16][kt * 32 + quad * 8];
                sa[kg] = __builtin_amdgcn_mfma_f32_16x16x32_bf16(aq[kt], bk, sa[kg], 0, 0, 0);
            }

        const float scale = 0.08838834764831845f;  // 1/sqrt(128)
        const bool diag = (t == qt);
        float p[4][4], al[4];
        for (int r = 0; r < 4; ++r) {
            int qrow = qbase + quad * 4 + r;
            float s0 = sa[0][r] * scale, s1 = sa[1][r] * scale;
            float s2 = sa[2][r] * scale, s3 = sa[3][r] * scale;
            if (diag) {
                if (kv0      + l16 > qrow) s0 = -1e30f;
                if (kv0 + 16 + l16 > qrow) s1 = -1e30f;
                if (kv0 + 32 + l16 > qrow) s2 = -1e30f;
                if (kv0 + 48 + l16 > qrow) s3 = -1e30f;
            }
            float rm = fmaxf(fmaxf(s0, s1), fmaxf(s2, s3));
            rm = fmaxf(rm, __shfl_xor(rm, 1));
            rm = fmaxf(rm, __shfl_xor(rm, 2));
            rm = fmaxf(rm, __shfl_xor(rm, 4));
            rm = fmaxf(rm, __shfl_xor(rm, 8));
            float mn = fmaxf(m_[r], rm);
            al[r] = __expf(m_[r] - mn);
            float p0 = __expf(s0 - mn), p1 = __expf(s1 - mn);
            float p2 = __expf(s2 - mn), p3 = __expf(s3 - mn);
            p[0][r] = p0; p[1][r] = p1; p[2][r] = p2; p[3][r] = p3;
            float rs = (p0 + p1) + (p2 + p3);
            rs += __shfl_xor(rs, 1);
            rs += __shfl_xor(rs, 2);
            rs += __shfl_xor(rs, 4);
            rs += __shfl_xor(rs, 8);
            l_[r] = l_[r] * al[r] + rs;
            m_[r] = mn;
        }
        for (int i = 0; i < 8; ++i)
            for (int r = 0; r < 4; ++r) o[i][r] *= al[r];

        // P: C-layout -> A-layout via per-wave LDS scratch (same-wave ordering)
        for (int kg = 0; kg < 4; ++kg)
            for (int r = 0; r < 4; ++r)
                Ps[w][quad * 4 + r][kg * 16 + l16] = f2bf(p[kg][r]);
        v8bf pa0 = *(const v8bf*)&Ps[w][l16][quad * 8];
        v8bf pa1 = *(const v8bf*)&Ps[w][l16][32 + quad * 8];
        for (int n8 = 0; n8 < 8; ++n8) {
            v8bf bv0 = *(const v8bf*)&Vt[n8 * 16 + l16][quad * 8];
            v8bf bv1 = *(const v8bf*)&Vt[n8 * 16 + l16][32 + quad * 8];
            o[n8] = __builtin_amdgcn_mfma_f32_16x16x32_bf16(pa0, bv0, o[n8], 0, 0, 0);
            o[n8] = __builtin_amdgcn_mfma_f32_16x16x32_bf16(pa1, bv1, o[n8], 0, 0, 0);
        }
    }

    for (int n8 = 0; n8 < 8; ++n8)
        for (int r = 0; r < 4; ++r) {
            int qg = qbase + quad * 4 + r;
            float val = o[n8][r] / l_[r];
            O[((size_t)(b * S_ + qg)) * HID_ + h * D_ + n8 * 16 + l16] = f2bf(val);
        }
}

// ---------------- launcher ------------------------------------------------
extern "C" void kernel_launch(void* const* d_in, const int* in_sizes, int n_in,
                              void* d_out, int out_size, void* d_ws, size_t ws_size,
                              hipStream_t stream) {
    const float* hid  = (const float*)d_in[0];
    const float* Wq   = (const float*)d_in[1];
    const float* Wk   = (const float*)d_in[2];
    const float* Wv   = (const float*)d_in[3];
    const float* Wo   = (const float*)d_in[4];
    const float* cosc = (const float*)d_in[5];
    const float* sinc = (const float*)d_in[6];
    // d_in[7] position_ids == arange, d_in[8] attention_mask == causal: implicit

    unsigned short* ws    = (unsigned short*)d_ws;
    // element offsets (bf16 = 2B each)
    unsigned short* wqkvT = ws;                                    // [6144][4096]  50.33 MB
    unsigned short* qbuf  = ws + (size_t)NQKV_ * HID_;             // [2][32][2048][128] 33.55 MB
    unsigned short* kbuf  = qbuf + (size_t)B_ * NH_ * S_ * D_;     // 8.39 MB
    unsigned short* vbuf  = kbuf + (size_t)B_ * NKV_ * S_ * D_;    // 8.39 MB
    unsigned short* hidB  = vbuf + (size_t)B_ * NKV_ * S_ * D_;    // [4096][4096] 33.55 MB -> peak 134.3 MB
    unsigned short* attn  = ws;                                    // alias wqkvT (dead after gemm1)
    unsigned short* woT   = ws + (size_t)M_ * HID_;                // alias wqkvT tail (dead after flash... after gemm1 actually)
    unsigned short* vTbuf = hidB;                                  // alias hidB (dead after gemm1), needs 8.39 MB

    // 1. hidden fp32 -> bf16
    cvt_f32_bf16<<<(M_ * HID_ / 4 + 255) / 256, 256, 0, stream>>>(hid, hidB, M_ * HID_ / 4);
    // 2. W^T staging: Wq|Wk|Wv transposed + converted
    transpose_f32_bf16<<<dim3(64, 64), 256, 0, stream>>>(Wq, wqkvT, HID_, HID_);
    transpose_f32_bf16<<<dim3(16, 64), 256, 0, stream>>>(Wk, wqkvT + (size_t)HID_ * HID_, HID_, NKV_ * D_);
    transpose_f32_bf16<<<dim3(16, 64), 256, 0, stream>>>(Wv, wqkvT + (size_t)(HID_ + NKV_ * D_) * HID_, HID_, NKV_ * D_);
    // 3. fused QKV projection, scatter to per-head layouts
    gemm_bt<0><<<dim3(NQKV_ / 128, M_ / 128), 256, 0, stream>>>(
        hidB, wqkvT, HID_, HID_, HID_, qbuf, kbuf, vbuf, nullptr);
    // 4. RoPE (in-place) + V transpose (hidB now dead -> vTbuf)
    rope_kernel<<<(B_ * NH_ * S_ * 64) / 256, 256, 0, stream>>>(qbuf, cosc, sinc, B_ * NH_ * S_ * 64);
    rope_kernel<<<(B_ * NKV_ * S_ * 64) / 256, 256, 0, stream>>>(kbuf, cosc, sinc, B_ * NKV_ * S_ * 64);
    transpose_v<<<dim3(S_ / 64, D_ / 64, B_ * NKV_), 256, 0, stream>>>(vbuf, vTbuf);
    // 5. causal flash attention -> attn [b,s,h*d] bf16 (reuses wqkvT region)
    flash_attn<<<dim3(S_ / 64, NH_, B_), 256, 0, stream>>>(qbuf, kbuf, vTbuf, attn);
    // 6. O projection: transpose Wo, then GEMM -> fp32 out
    transpose_f32_bf16<<<dim3(64, 64), 256, 0, stream>>>(Wo, woT, HID_, HID_);
    gemm_bt<1><<<dim3(HID_ / 128, M_ / 128), 256, 0, stream>>>(
        attn, woT, HID_, HID_, HID_, nullptr, nullptr, nullptr, (float*)d_out);
}